// Round 15
// baseline (113.665 us; speedup 1.0000x reference)
//
#include <hip/hip_runtime.h>
#include <math.h>

// Problem constants: L=16384, H=256, P=512.
#define L_SEQ 16384
#define H_DIM 256
#define P_DIM 512
#define CL 32                 // scan chunk length
#define NC (L_SEQ / CL)       // 512 chunks

typedef __attribute__((ext_vector_type(8))) short bf16x8;   // MFMA A/B fragment (4 VGPR)
typedef __attribute__((ext_vector_type(4))) float f32x4;    // MFMA C/D fragment

static __device__ __forceinline__ unsigned short f2bf(float f) {
  unsigned int u = __builtin_bit_cast(unsigned int, f);
  u += 0x7FFFu + ((u >> 16) & 1u);
  return (unsigned short)(u >> 16);
}
static __device__ __forceinline__ float bflo(unsigned int v) {
  return __builtin_bit_cast(float, v << 16);
}
static __device__ __forceinline__ float bfhi(unsigned int v) {
  return __builtin_bit_cast(float, v & 0xFFFF0000u);
}

// Weights stored K-PACKED: unit = (k>>3)*N + n, element = unit*8 + (k&7).
//
// Merged prep (branch by blockIdx, wave-uniform):
//  [0,2): params; [2,1026): W1b_r; [1026,2050): W2b_r;
//  [2050,6146): cast u->ub AND out = u*D (split-K base term, exactly once)
__global__ __launch_bounds__(256) void prep_all(
    const float* __restrict__ A_diag, const float* __restrict__ G_diag,
    const float* __restrict__ dt, const float* __restrict__ B,
    const float* __restrict__ C, const float* __restrict__ u,
    const float* __restrict__ Dv,
    float* __restrict__ prm, unsigned short* __restrict__ W1b,
    unsigned short* __restrict__ W2b, unsigned short* __restrict__ ub,
    float* __restrict__ out) {
  const int b = blockIdx.x;
  const int t = threadIdx.x;
  if (b < 2) {
    int p = b * 256 + t;
    float dts = 1.0f / (1.0f + expf(-dt[p]));
    float G = fmaxf(G_diag[p], 0.0f);
    float g = dts * G;
    float root = sqrtf(1.0f - g);
    float denom = fmaxf(dts * dts, 1e-6f);
    float A_low  = (2.0f - g - 2.0f * root) / denom;
    float A_high = (2.0f - g + 2.0f * root) / denom;
    float Ad = A_diag[p];
    float A = A_low + fmaxf(Ad - A_low, 0.0f) - fmaxf(Ad - A_high, 0.0f);
    float m00 = 1.0f - g;
    float m01 = -dts * A;
    float m10 = dts * (1.0f - g);
    float m11 = 1.0f - dts * dts * A;
    float c00 = m00, c01 = m01, c10 = m10, c11 = m11;
#pragma unroll
    for (int i = 0; i < 5; i++) {   // M^32 by squaring (CL=32); rho(M)<=1
      float n00 = c00 * c00 + c01 * c10;
      float n01 = c00 * c01 + c01 * c11;
      float n10 = c10 * c00 + c11 * c10;
      float n11 = c10 * c01 + c11 * c11;
      c00 = n00; c01 = n01; c10 = n10; c11 = n11;
    }
    prm[0 * P_DIM + p] = m00;
    prm[1 * P_DIM + p] = m01;
    prm[2 * P_DIM + p] = m10;
    prm[3 * P_DIM + p] = m11;
    prm[4 * P_DIM + p] = dts;
    prm[5 * P_DIM + p] = dts * dts;
    prm[6 * P_DIM + p] = c00;
    prm[7 * P_DIM + p] = c01;
    prm[8 * P_DIM + p] = c10;
    prm[9 * P_DIM + p] = c11;
  } else if (b < 2 + 1024) {
    int idx = (b - 2) * 256 + t;          // n=2p+c in [0,1024), k=h in [0,256)
    int n = idx >> 8;
    int k = idx & 255;
    int p = n >> 1, c = n & 1;
    W1b[((size_t)(k >> 3) * 1024 + n) * 8 + (k & 7)] = f2bf(B[(p * H_DIM + k) * 2 + c]);
  } else if (b < 2 + 2048) {
    int idx = (b - 1026) * 256 + t;       // n=h in [0,256), k=2p+c in [0,1024)
    int h = idx >> 10;
    int k = idx & 1023;
    int p = k >> 1, c = k & 1;
    float v = C[(h * P_DIM + p) * 2 + c];
    W2b[((size_t)(k >> 3) * 256 + h) * 8 + (k & 7)] = f2bf(c ? -v : v);
  } else {
    int idx = (b - 2050) * 256 + t;       // cast u + init out = u*D
    float4 v = ((const float4*)u)[idx];
    ushort4 o;
    o.x = f2bf(v.x); o.y = f2bf(v.y); o.z = f2bf(v.z); o.w = f2bf(v.w);
    ((ushort4*)ub)[idx] = o;
    const int col = (idx * 4) & (H_DIM - 1);        // aligned: idx*4 % 4 == 0
    float4 d = *(const float4*)(Dv + col);
    float4 ov = make_float4(v.x * d.x, v.y * d.y, v.z * d.z, v.w * d.w);
    ((float4*)out)[idx] = ov;
  }
}

// GEMM1 + fused local scan. 128x128 tile, 256 threads = 4 waves (2x2), BK=32.
// LDS tiles k-packed [kg][row][8] -> conflict-free fragment reads.
// Epilogue stages the C-tile in LDS (padded stride 132) for the fused local scan.
__global__ __launch_bounds__(256) void gemm1_scan(
    const unsigned short* __restrict__ A, const unsigned short* __restrict__ W,
    unsigned short* __restrict__ Out,           // Bu16, N=1024
    const float* __restrict__ prm, float4* __restrict__ finals) {
  constexpr int N = 1024, K = H_DIM;
  __shared__ unsigned short tA[128 * 32];    // 8KB k-packed [kg][r][8]
  __shared__ unsigned short tW[128 * 32];    // 8KB k-packed [kg][n][8]
  __shared__ unsigned short stg[128 * 132];  // 33KB C-tile stage, padded stride
  const int tid = threadIdx.x;
  const int lane = tid & 63;
  const int wid = tid >> 6;
  const int wr = wid >> 1;
  const int wc = wid & 1;
  const int bm = blockIdx.x * 128;
  const int bn = blockIdx.y * 128;

  f32x4 acc[4][4] = {};
  const int rA = lane & 15;
  const int g = lane >> 4;

  for (int k0 = 0; k0 < K; k0 += 32) {
    __syncthreads();
#pragma unroll
    for (int c = wid; c < 8; c += 4) {        // A-tile: 512 units (kg*128 + r)
      const int unit = c * 64 + lane;
      const int kg = unit >> 7, r = unit & 127;
      const unsigned short* src = A + ((size_t)(bm + r) * 32 + (k0 >> 3) + kg) * 8;
      __builtin_amdgcn_global_load_lds(
          (const __attribute__((address_space(1))) void*)src,
          (__attribute__((address_space(3))) void*)(tA + c * 512), 16, 0, 0);
    }
#pragma unroll
    for (int c = wid; c < 8; c += 4) {        // W-tile: 512 units (kg*128 + n)
      const int unit = c * 64 + lane;
      const int kg = unit >> 7, n = unit & 127;
      const unsigned short* src = W + ((size_t)((k0 >> 3) + kg) * 1024 + bn + n) * 8;
      __builtin_amdgcn_global_load_lds(
          (const __attribute__((address_space(1))) void*)src,
          (__attribute__((address_space(3))) void*)(tW + c * 512), 16, 0, 0);
    }
    __syncthreads();

    bf16x8 af[4], wf[4];
#pragma unroll
    for (int i = 0; i < 4; i++)
      af[i] = *(const bf16x8*)&tA[(g * 128 + wr * 64 + i * 16 + rA) * 8];
#pragma unroll
    for (int j = 0; j < 4; j++)
      wf[j] = *(const bf16x8*)&tW[(g * 128 + wc * 64 + j * 16 + rA) * 8];
#pragma unroll
    for (int i = 0; i < 4; i++)
#pragma unroll
      for (int j = 0; j < 4; j++)
        acc[i][j] = __builtin_amdgcn_mfma_f32_16x16x32_bf16(af[i], wf[j], acc[i][j], 0, 0, 0);
  }

  // C/D layout: col = lane&15, row = (lane>>4)*4 + q  [m89-verified]
  const int cr = (lane >> 4) * 4;
  const int cc = lane & 15;
#pragma unroll
  for (int i = 0; i < 4; i++)
#pragma unroll
    for (int j = 0; j < 4; j++) {
      const int rl = wr * 64 + i * 16 + cr;          // local row
      const int clc = wc * 64 + j * 16 + cc;         // local col
#pragma unroll
      for (int q = 0; q < 4; q++) {
        const unsigned short hv = f2bf(acc[i][j][q]);
        Out[(size_t)(bm + rl + q) * N + bn + clc] = hv;
        stg[(rl + q) * 132 + clc] = hv;              // LDS stage for fused scan
      }
    }

  // ---- fused local scan over this block's 4 chunks x 64 p-states (from LDS)
  __syncthreads();
  {
    const int i = tid >> 6;            // chunk within tile (0..3) — one per wave
    const int pl = tid & 63;           // p within tile
    const int p = (bn >> 1) + pl;      // global p
    const int cglob = blockIdx.x * 4 + i;
    float m00 = prm[0 * P_DIM + p], m01 = prm[1 * P_DIM + p];
    float m10 = prm[2 * P_DIM + p], m11 = prm[3 * P_DIM + p];
    float dts = prm[4 * P_DIM + p], dts2 = prm[5 * P_DIM + p];
    float x1r = 0.f, x2r = 0.f, x1i = 0.f, x2i = 0.f;
    const unsigned int* stg32 = (const unsigned int*)stg;   // dword idx = row*66 + pl
#pragma unroll 8
    for (int s = 0; s < CL; s++) {
      unsigned int v = stg32[(i * 32 + s) * 66 + pl];
      float bx = bflo(v), by = bfhi(v);
      float n1r = fmaf(m00, x1r, fmaf(m01, x2r, dts * bx));
      float n2r = fmaf(m10, x1r, fmaf(m11, x2r, dts2 * bx));
      float n1i = fmaf(m00, x1i, fmaf(m01, x2i, dts * by));
      float n2i = fmaf(m10, x1i, fmaf(m11, x2i, dts2 * by));
      x1r = n1r; x2r = n2r; x1i = n1i; x2i = n2i;
    }
    finals[(size_t)cglob * P_DIM + p] = make_float4(x1r, x2r, x1i, x2i);
  }
}

// Phase B: Hillis-Steele over NC=512 chunks, one block per p, 512 threads.
__global__ __launch_bounds__(NC) void scan_carry(
    const float4* __restrict__ finals, const float* __restrict__ prm,
    float4* __restrict__ carry) {
  int p = blockIdx.x;
  int c = threadIdx.x;
  __shared__ float4 sb[NC];
  float m00 = prm[6 * P_DIM + p], m01 = prm[7 * P_DIM + p];
  float m10 = prm[8 * P_DIM + p], m11 = prm[9 * P_DIM + p];
  float4 b = finals[c * P_DIM + p];
  for (int o = 1; o < NC; o <<= 1) {
    sb[c] = b;
    __syncthreads();
    float4 nb = (c >= o) ? sb[c - o] : make_float4(0.f, 0.f, 0.f, 0.f);
    __syncthreads();
    b.x = fmaf(m00, nb.x, fmaf(m01, nb.y, b.x));
    b.y = fmaf(m10, nb.x, fmaf(m11, nb.y, b.y));
    b.z = fmaf(m00, nb.z, fmaf(m01, nb.w, b.z));
    b.w = fmaf(m10, nb.z, fmaf(m11, nb.w, b.w));
    float n00 = m00 * m00 + m01 * m10;
    float n01 = m00 * m01 + m01 * m11;
    float n10 = m10 * m00 + m11 * m10;
    float n11 = m10 * m01 + m11 * m11;
    m00 = n00; m01 = n01; m10 = n10; m11 = n11;
  }
  if (c + 1 < NC) carry[(c + 1) * P_DIM + p] = b;
  if (c == 0) carry[p] = make_float4(0.f, 0.f, 0.f, 0.f);
}

// GEMM2 split-K, v4: block = 128 rows x 256 cols x K-slice 256 (p-slice 128).
// Grid (128, 4) = 512 blocks, 2/CU. Wave (2x2) = 64r x 128c:
// per K-step af[4] + wf[8] -> 32 MFMA per 12 fragment loads (vs 1:1 before).
// Prologue: recompute ys for (row-strip, p-slice) only -> yA 128x128 uint = 64KB.
// wf direct from k-packed W2b (L1/L2-hot). Epilogue: atomicAdd into out
// (pre-initialized to u*D by prep_all; fp32 atomics device-scope).
__global__ __launch_bounds__(256) void gemm2_sk(
    const unsigned int* __restrict__ Bu16, const float* __restrict__ prm,
    const float4* __restrict__ carry, const unsigned short* __restrict__ W2b,
    float* __restrict__ out) {
  __shared__ unsigned int yA[128 * 128];   // 64KB: ys[row][pl] packed bf16, swizzled
  const int tid = threadIdx.x;
  const int lane = tid & 63;
  const int wid = tid >> 6;
  const int row0 = blockIdx.x * 128;       // row strip (4 chunks)
  const int ks = blockIdx.y;               // k-slice 0..3  <-> p-slice ks*128
  const int p0 = ks * 128;

  // ---- prologue: 512 (chunk, p) states, 2 per thread
#pragma unroll
  for (int h = 0; h < 2; h++) {
    const int idx = h * 256 + tid;
    const int i = idx >> 7;                // chunk-local 0..3
    const int pl = idx & 127;              // p within slice
    const int p = p0 + pl;
    float m00 = prm[0 * P_DIM + p], m01 = prm[1 * P_DIM + p];
    float m10 = prm[2 * P_DIM + p], m11 = prm[3 * P_DIM + p];
    float dts = prm[4 * P_DIM + p], dts2 = prm[5 * P_DIM + p];
    float4 s = carry[(size_t)(blockIdx.x * 4 + i) * P_DIM + p];
    float x1r = s.x, x2r = s.y, x1i = s.z, x2i = s.w;
    const unsigned int* src = Bu16 + (size_t)(row0 + i * 32) * P_DIM + p;
#pragma unroll 8
    for (int st = 0; st < 32; st++) {
      unsigned int v = src[(size_t)st * P_DIM];
      float bx = bflo(v), by = bfhi(v);
      float n1r = fmaf(m00, x1r, fmaf(m01, x2r, dts * bx));
      float n2r = fmaf(m10, x1r, fmaf(m11, x2r, dts2 * bx));
      float n1i = fmaf(m00, x1i, fmaf(m01, x2i, dts * by));
      float n2i = fmaf(m10, x1i, fmaf(m11, x2i, dts2 * by));
      const int row = i * 32 + st;
      // swizzle: uint idx (row*128+pl) ^ ((row&7)<<2)  == byte ^ ((row&7)<<4)
      yA[(row * 128 + pl) ^ ((row & 7) << 2)] =
          (unsigned int)f2bf(n2r) | ((unsigned int)f2bf(n2i) << 16);
      x1r = n1r; x2r = n2r; x1i = n1i; x2i = n2i;
    }
  }
  __syncthreads();   // the only barrier

  // ---- K-loop: 8 steps of 32 k-local; wave (wr,wc) = 64r x 128c
  const int wr = wid >> 1;
  const int wc = wid & 1;
  const int rA = lane & 15;
  const int g = lane >> 4;
  const unsigned short* yAs = (const unsigned short*)yA;
  // lane-invariant W2b base (shorts): unit = (ks*32 + g)*256 + wc*128 + rA
  const unsigned short* wbase = W2b + (((size_t)ks * 32 + g) * 256 + wc * 128 + rA) * 8;
  f32x4 acc[4][8] = {};

#pragma unroll 2
  for (int t = 0; t < 8; t++) {
    bf16x8 af[4];
#pragma unroll
    for (int m = 0; m < 4; m++) {
      const int r = wr * 64 + m * 16 + rA;
      af[m] = *(const bf16x8*)&yAs[((unsigned)(r * 256 + t * 32 + g * 8)) ^ ((r & 7) << 3)];
    }
#pragma unroll
    for (int j = 0; j < 8; j++) {
      bf16x8 wf = *(const bf16x8*)&wbase[(size_t)t * 8192 + j * 128];
#pragma unroll
      for (int m = 0; m < 4; m++)
        acc[m][j] = __builtin_amdgcn_mfma_f32_16x16x32_bf16(af[m], wf, acc[m][j], 0, 0, 0);
    }
  }

  // ---- epilogue: atomicAdd partials (C/D: col=lane&15, row=(lane>>4)*4+q)
  const int cr = (lane >> 4) * 4;
  const int cc = lane & 15;
#pragma unroll
  for (int m = 0; m < 4; m++)
#pragma unroll
    for (int j = 0; j < 8; j++) {
      const int rowg = row0 + wr * 64 + m * 16 + cr;
      const int col = wc * 128 + j * 16 + cc;
#pragma unroll
      for (int q = 0; q < 4; q++)
        atomicAdd(&out[(size_t)(rowg + q) * H_DIM + col], acc[m][j][q]);
    }
}

extern "C" void kernel_launch(void* const* d_in, const int* in_sizes, int n_in,
                              void* d_out, int out_size, void* d_ws, size_t ws_size,
                              hipStream_t stream) {
  const float* u      = (const float*)d_in[0];  // (L, H)
  const float* A_diag = (const float*)d_in[1];
  const float* G_diag = (const float*)d_in[2];
  const float* dt     = (const float*)d_in[3];
  const float* B      = (const float*)d_in[4];  // (P, H, 2)
  const float* C      = (const float*)d_in[5];  // (H, P, 2)
  const float* D      = (const float*)d_in[6];  // (H,)
  float* out = (float*)d_out;

  // Workspace: Bu16 33.55MB | ub 8.39MB | W1b 0.5MB | W2b 0.5MB | prm | finals 4MB | carry 4MB (~51MB)
  char* w = (char*)d_ws;
  unsigned short* Bu16 = (unsigned short*)w;                               // L*1024 bf16
  unsigned short* ub   = (unsigned short*)(w + (size_t)L_SEQ * 1024 * 2);  // L*256 bf16
  unsigned short* W1b  = ub + (size_t)L_SEQ * H_DIM;                       // 1024*256 (k-packed)
  unsigned short* W2b  = W1b + 1024 * H_DIM;                               // 256*1024 (k-packed)
  float* prm    = (float*)(W2b + H_DIM * 1024);                            // 10*512 (pad 8192)
  float* finals = prm + 8192;                                              // NC*P*4
  float* carryb = finals + (size_t)NC * P_DIM * 4;                         // NC*P*4

  prep_all<<<2 + 1024 + 1024 + 4096, 256, 0, stream>>>(
      A_diag, G_diag, dt, B, C, u, D, prm, W1b, W2b, ub, out);

  // GEMM1 + fused local scan (k-packed LDS tiles)
  gemm1_scan<<<dim3(L_SEQ / 128, 1024 / 128), 256, 0, stream>>>(
      ub, W1b, Bu16, prm, (float4*)finals);

  scan_carry<<<P_DIM, NC, 0, stream>>>(
      (const float4*)finals, prm, (float4*)carryb);

  // GEMM2 split-K + fused scan_final: grid (128 strips, 4 k-slices)
  gemm2_sk<<<dim3(L_SEQ / 128, 4), 256, 0, stream>>>(
      (const unsigned int*)Bu16, prm, (const float4*)carryb, W2b, out);
}

// Round 16
// 88.239 us; speedup vs baseline: 1.2881x; 1.2881x over previous
//
#include <hip/hip_runtime.h>
#include <math.h>

// Problem constants: L=16384, H=256, P=512.
#define L_SEQ 16384
#define H_DIM 256
#define P_DIM 512
#define CL 32                 // scan chunk length
#define NC (L_SEQ / CL)       // 512 chunks

typedef __attribute__((ext_vector_type(8))) short bf16x8;   // MFMA A/B fragment (4 VGPR)
typedef __attribute__((ext_vector_type(4))) float f32x4;    // MFMA C/D fragment

static __device__ __forceinline__ unsigned short f2bf(float f) {
  unsigned int u = __builtin_bit_cast(unsigned int, f);
  u += 0x7FFFu + ((u >> 16) & 1u);
  return (unsigned short)(u >> 16);
}
static __device__ __forceinline__ float bflo(unsigned int v) {
  return __builtin_bit_cast(float, v << 16);
}
static __device__ __forceinline__ float bfhi(unsigned int v) {
  return __builtin_bit_cast(float, v & 0xFFFF0000u);
}
static __device__ __forceinline__ float bf2f(unsigned short s) {
  return __builtin_bit_cast(float, (unsigned int)s << 16);
}
static __device__ __forceinline__ unsigned int pack2(float r, float i) {
  return (unsigned int)f2bf(r) | ((unsigned int)f2bf(i) << 16);
}

// Weights K-PACKED: unit = (k>>3)*N + n, element = unit*8 + (k&7).
// prep branches: [0,2): params + a/b tables (row2 of M^{t+1}, t=0..31);
// [2,1026): W1b; [1026,2050): W2b; [2050,6146): cast u->ub.
__global__ __launch_bounds__(256) void prep_all(
    const float* __restrict__ A_diag, const float* __restrict__ G_diag,
    const float* __restrict__ dt, const float* __restrict__ B,
    const float* __restrict__ C, const float* __restrict__ u,
    float* __restrict__ prm, unsigned short* __restrict__ W1b,
    unsigned short* __restrict__ W2b, unsigned short* __restrict__ ub,
    float* __restrict__ aT, float* __restrict__ bT) {
  const int b = blockIdx.x;
  const int t = threadIdx.x;
  if (b < 2) {
    int p = b * 256 + t;
    float dts = 1.0f / (1.0f + expf(-dt[p]));
    float G = fmaxf(G_diag[p], 0.0f);
    float g = dts * G;
    float root = sqrtf(1.0f - g);
    float denom = fmaxf(dts * dts, 1e-6f);
    float A_low  = (2.0f - g - 2.0f * root) / denom;
    float A_high = (2.0f - g + 2.0f * root) / denom;
    float Ad = A_diag[p];
    float A = A_low + fmaxf(Ad - A_low, 0.0f) - fmaxf(Ad - A_high, 0.0f);
    float m00 = 1.0f - g;
    float m01 = -dts * A;
    float m10 = dts * (1.0f - g);
    float m11 = 1.0f - dts * dts * A;
    // a/b tables: cur = M^{t+1}, store its second row; cur = M*cur
    float e00 = m00, e01 = m01, e10 = m10, e11 = m11;
    for (int s = 0; s < 32; s++) {
      aT[s * P_DIM + p] = e10;
      bT[s * P_DIM + p] = e11;
      float f00 = m00 * e00 + m01 * e10;
      float f01 = m00 * e01 + m01 * e11;
      float f10 = m10 * e00 + m11 * e10;
      float f11 = m10 * e01 + m11 * e11;
      e00 = f00; e01 = f01; e10 = f10; e11 = f11;
    }
    // Mc = M^32 (5 squarings)
    float c00 = m00, c01 = m01, c10 = m10, c11 = m11;
#pragma unroll
    for (int i = 0; i < 5; i++) {
      float n00 = c00 * c00 + c01 * c10;
      float n01 = c00 * c01 + c01 * c11;
      float n10 = c10 * c00 + c11 * c10;
      float n11 = c10 * c01 + c11 * c11;
      c00 = n00; c01 = n01; c10 = n10; c11 = n11;
    }
    prm[0 * P_DIM + p] = m00;
    prm[1 * P_DIM + p] = m01;
    prm[2 * P_DIM + p] = m10;
    prm[3 * P_DIM + p] = m11;
    prm[4 * P_DIM + p] = dts;
    prm[5 * P_DIM + p] = dts * dts;
    prm[6 * P_DIM + p] = c00;
    prm[7 * P_DIM + p] = c01;
    prm[8 * P_DIM + p] = c10;
    prm[9 * P_DIM + p] = c11;
  } else if (b < 2 + 1024) {
    int idx = (b - 2) * 256 + t;          // n=2p+c in [0,1024), k=h in [0,256)
    int n = idx >> 8;
    int k = idx & 255;
    int p = n >> 1, c = n & 1;
    W1b[((size_t)(k >> 3) * 1024 + n) * 8 + (k & 7)] = f2bf(B[(p * H_DIM + k) * 2 + c]);
  } else if (b < 2 + 2048) {
    int idx = (b - 1026) * 256 + t;       // n=h in [0,256), k=2p+c in [0,1024)
    int h = idx >> 10;
    int k = idx & 1023;
    int p = k >> 1, c = k & 1;
    float v = C[(h * P_DIM + p) * 2 + c];
    W2b[((size_t)(k >> 3) * 256 + h) * 8 + (k & 7)] = f2bf(c ? -v : v);
  } else {
    int idx = (b - 2050) * 256 + t;       // cast u
    float4 v = ((const float4*)u)[idx];
    ushort4 o;
    o.x = f2bf(v.x); o.y = f2bf(v.y); o.z = f2bf(v.z); o.w = f2bf(v.w);
    ((ushort4*)ub)[idx] = o;
  }
}

// GEMM1 + fused local scan. 128x128 tile, 4 waves, BK=32, k-packed LDS.
// NO Bu global write: C-tile goes to LDS stg only; the fused scan then writes
// ys_local (pre-carry x2 per t, packed bf16) + chunk finals.
__global__ __launch_bounds__(256) void gemm1_scan(
    const unsigned short* __restrict__ A, const unsigned short* __restrict__ W,
    unsigned int* __restrict__ ys,              // ys_local, [L][512] packed
    const float* __restrict__ prm, float4* __restrict__ finals) {
  constexpr int K = H_DIM;
  __shared__ unsigned short tA[128 * 32];    // 8KB k-packed [kg][r][8]
  __shared__ unsigned short tW[128 * 32];    // 8KB k-packed [kg][n][8]
  __shared__ unsigned short stg[128 * 132];  // 33KB C-tile stage, padded stride
  const int tid = threadIdx.x;
  const int lane = tid & 63;
  const int wid = tid >> 6;
  const int wr = wid >> 1;
  const int wc = wid & 1;
  const int bm = blockIdx.x * 128;
  const int bn = blockIdx.y * 128;

  f32x4 acc[4][4] = {};
  const int rA = lane & 15;
  const int g = lane >> 4;

  for (int k0 = 0; k0 < K; k0 += 32) {
    __syncthreads();
#pragma unroll
    for (int c = wid; c < 8; c += 4) {        // A-tile: 512 units (kg*128 + r)
      const int unit = c * 64 + lane;
      const int kg = unit >> 7, r = unit & 127;
      const unsigned short* src = A + ((size_t)(bm + r) * 32 + (k0 >> 3) + kg) * 8;
      __builtin_amdgcn_global_load_lds(
          (const __attribute__((address_space(1))) void*)src,
          (__attribute__((address_space(3))) void*)(tA + c * 512), 16, 0, 0);
    }
#pragma unroll
    for (int c = wid; c < 8; c += 4) {        // W-tile: 512 units (kg*128 + n)
      const int unit = c * 64 + lane;
      const int kg = unit >> 7, n = unit & 127;
      const unsigned short* src = W + ((size_t)((k0 >> 3) + kg) * 1024 + bn + n) * 8;
      __builtin_amdgcn_global_load_lds(
          (const __attribute__((address_space(1))) void*)src,
          (__attribute__((address_space(3))) void*)(tW + c * 512), 16, 0, 0);
    }
    __syncthreads();

    bf16x8 af[4], wf[4];
#pragma unroll
    for (int i = 0; i < 4; i++)
      af[i] = *(const bf16x8*)&tA[(g * 128 + wr * 64 + i * 16 + rA) * 8];
#pragma unroll
    for (int j = 0; j < 4; j++)
      wf[j] = *(const bf16x8*)&tW[(g * 128 + wc * 64 + j * 16 + rA) * 8];
#pragma unroll
    for (int i = 0; i < 4; i++)
#pragma unroll
      for (int j = 0; j < 4; j++)
        acc[i][j] = __builtin_amdgcn_mfma_f32_16x16x32_bf16(af[i], wf[j], acc[i][j], 0, 0, 0);
  }

  // C-tile -> LDS stage only (C/D: col=lane&15, row=(lane>>4)*4+q)
  const int cr = (lane >> 4) * 4;
  const int cc = lane & 15;
#pragma unroll
  for (int i = 0; i < 4; i++)
#pragma unroll
    for (int j = 0; j < 4; j++) {
      const int rl = wr * 64 + i * 16 + cr;
      const int clc = wc * 64 + j * 16 + cc;
#pragma unroll
      for (int q = 0; q < 4; q++)
        stg[(rl + q) * 132 + clc] = f2bf(acc[i][j][q]);
    }

  // ---- fused local scan: 4 chunks x 64 p; writes ys_local + finals
  __syncthreads();
  {
    const int i = tid >> 6;            // chunk within tile (0..3)
    const int pl = tid & 63;
    const int p = (bn >> 1) + pl;
    const int cglob = blockIdx.x * 4 + i;
    float m00 = prm[0 * P_DIM + p], m01 = prm[1 * P_DIM + p];
    float m10 = prm[2 * P_DIM + p], m11 = prm[3 * P_DIM + p];
    float dts = prm[4 * P_DIM + p], dts2 = prm[5 * P_DIM + p];
    float x1r = 0.f, x2r = 0.f, x1i = 0.f, x2i = 0.f;
    const unsigned int* stg32 = (const unsigned int*)stg;   // dword idx = row*66 + pl
    unsigned int* dst = ys + (size_t)(bm + i * 32) * P_DIM + p;
#pragma unroll 8
    for (int s = 0; s < CL; s++) {
      unsigned int v = stg32[(i * 32 + s) * 66 + pl];
      float bx = bflo(v), by = bfhi(v);
      float n1r = fmaf(m00, x1r, fmaf(m01, x2r, dts * bx));
      float n2r = fmaf(m10, x1r, fmaf(m11, x2r, dts2 * bx));
      float n1i = fmaf(m00, x1i, fmaf(m01, x2i, dts * by));
      float n2i = fmaf(m10, x1i, fmaf(m11, x2i, dts2 * by));
      dst[(size_t)s * P_DIM] = pack2(n2r, n2i);   // ys_local = x2 (pre-carry)
      x1r = n1r; x2r = n2r; x1i = n1i; x2i = n2i;
    }
    finals[(size_t)cglob * P_DIM + p] = make_float4(x1r, x2r, x1i, x2i);
  }
}

// Phase B: Hillis-Steele over NC=512 chunks, one block per p, 512 threads.
__global__ __launch_bounds__(NC) void scan_carry(
    const float4* __restrict__ finals, const float* __restrict__ prm,
    float4* __restrict__ carry) {
  int p = blockIdx.x;
  int c = threadIdx.x;
  __shared__ float4 sb[NC];
  float m00 = prm[6 * P_DIM + p], m01 = prm[7 * P_DIM + p];
  float m10 = prm[8 * P_DIM + p], m11 = prm[9 * P_DIM + p];
  float4 b = finals[c * P_DIM + p];
  for (int o = 1; o < NC; o <<= 1) {
    sb[c] = b;
    __syncthreads();
    float4 nb = (c >= o) ? sb[c - o] : make_float4(0.f, 0.f, 0.f, 0.f);
    __syncthreads();
    b.x = fmaf(m00, nb.x, fmaf(m01, nb.y, b.x));
    b.y = fmaf(m10, nb.x, fmaf(m11, nb.y, b.y));
    b.z = fmaf(m00, nb.z, fmaf(m01, nb.w, b.z));
    b.w = fmaf(m10, nb.z, fmaf(m11, nb.w, b.w));
    float n00 = m00 * m00 + m01 * m10;
    float n01 = m00 * m01 + m01 * m11;
    float n10 = m10 * m00 + m11 * m10;
    float n11 = m10 * m01 + m11 * m11;
    m00 = n00; m01 = n01; m10 = n10; m11 = n11;
  }
  if (c + 1 < NC) carry[(c + 1) * P_DIM + p] = b;
  if (c == 0) carry[p] = make_float4(0.f, 0.f, 0.f, 0.f);
}

// Elementwise carry correction, in-place: ys[t][p] += a[t&31][p]*x1in + b*x2in
// (re and im share real coefficients). Fully parallel, coalesced uint4.
__global__ __launch_bounds__(256) void correct_ys(
    unsigned int* __restrict__ ys, const float4* __restrict__ carry,
    const float* __restrict__ aT, const float* __restrict__ bT) {
  const int i4 = blockIdx.x * 256 + threadIdx.x;   // uint4 index
  const int tg = i4 >> 7;                          // global row t
  const int p0 = (i4 & 127) * 4;
  const int c = tg >> 5, t = tg & 31;
  uint4 v = ((const uint4*)ys)[i4];
  const float4 a = *(const float4*)&aT[t * P_DIM + p0];
  const float4 b = *(const float4*)&bT[t * P_DIM + p0];
  const float4* cb = carry + (size_t)c * P_DIM + p0;
  float4 x0 = cb[0], x1 = cb[1], x2 = cb[2], x3 = cb[3];
  v.x = pack2(bflo(v.x) + a.x * x0.x + b.x * x0.y, bfhi(v.x) + a.x * x0.z + b.x * x0.w);
  v.y = pack2(bflo(v.y) + a.y * x1.x + b.y * x1.y, bfhi(v.y) + a.y * x1.z + b.y * x1.w);
  v.z = pack2(bflo(v.z) + a.z * x2.x + b.z * x2.y, bfhi(v.z) + a.z * x2.z + b.z * x2.w);
  v.w = pack2(bflo(v.w) + a.w * x3.x + b.w * x3.y, bfhi(v.w) + a.w * x3.z + b.w * x3.w);
  ((uint4*)ys)[i4] = v;
}

// GEMM2 lean: out[L][256] = ys[L][1024k] @ W2b^T + ub*D.
// 64x128 tile, grid (256,2)=512 blocks, 24KB LDS -> high residency, 2-phase
// double-buffered A+W global_load_lds (prefetch issued BEFORE compute).
// A LDS: [row][4 segs of 16B], seg XOR-swizzled by (row>>1)&3 (rule #21:
// linear dest, permuted per-lane SOURCE, same permutation on READ) -> 2/bank.
// W LDS: k-packed [kg][n][8] -> conflict-free.
__global__ __launch_bounds__(256) void gemm2_lean(
    const unsigned short* __restrict__ ys16, const unsigned short* __restrict__ W2b,
    const unsigned short* __restrict__ ub, const float* __restrict__ Dv,
    float* __restrict__ out) {
  __shared__ unsigned short tA[2][64 * 32];    // 2 x 4KB
  __shared__ unsigned short tW[2][128 * 32];   // 2 x 8KB
  const int tid = threadIdx.x;
  const int lane = tid & 63;
  const int wid = tid >> 6;
  const int bm = blockIdx.x * 64;
  const int bn = blockIdx.y * 128;

  const int rA = lane & 15;
  const int g = lane >> 4;
  const int wr = wid >> 1;          // row half (32 rows)
  const int wc = wid & 1;           // col half (64 cols)

  // staging lane geometry
  const int a_row = (wid * 64 + lane) >> 2;        // 0..63
  const int a_sd = (wid * 64 + lane) & 3;          // dest seg
  const int a_ss = a_sd ^ ((a_row >> 1) & 3);      // source seg (involution)

  auto STAGE = [&](int buf, int k0) {
    // A: 256 units of 16B, one gload per wave (base wave-uniform)
    {
      const unsigned short* src = ys16 + (size_t)(bm + a_row) * 1024 + k0 + a_ss * 8;
      __builtin_amdgcn_global_load_lds(
          (const __attribute__((address_space(1))) void*)src,
          (__attribute__((address_space(3))) void*)(&tA[buf][wid * 512]), 16, 0, 0);
    }
    // W: 512 units (kg*128+n), two gloads per wave
#pragma unroll
    for (int c = wid; c < 8; c += 4) {
      const int unit = c * 64 + lane;
      const int kg = unit >> 7, n = unit & 127;
      const unsigned short* src = W2b + (((size_t)(k0 >> 3) + kg) * 256 + bn + n) * 8;
      __builtin_amdgcn_global_load_lds(
          (const __attribute__((address_space(1))) void*)src,
          (__attribute__((address_space(3))) void*)(&tW[buf][c * 512]), 16, 0, 0);
    }
  };

  f32x4 acc[2][4] = {};
  STAGE(0, 0);
  __syncthreads();

  for (int t = 0; t < 32; t++) {
    const int cur = t & 1;
    if (t < 31) STAGE(cur ^ 1, (t + 1) * 32);   // prefetch BEFORE compute
    bf16x8 af[2], wf[4];
#pragma unroll
    for (int m = 0; m < 2; m++) {
      const int r = wr * 32 + m * 16 + rA;
      const int unit = r * 4 + (g ^ ((r >> 1) & 3));
      af[m] = *(const bf16x8*)&tA[cur][unit * 8];
    }
#pragma unroll
    for (int j = 0; j < 4; j++)
      wf[j] = *(const bf16x8*)&tW[cur][(g * 128 + wc * 64 + j * 16 + rA) * 8];
#pragma unroll
    for (int m = 0; m < 2; m++)
#pragma unroll
      for (int j = 0; j < 4; j++)
        acc[m][j] = __builtin_amdgcn_mfma_f32_16x16x32_bf16(af[m], wf[j], acc[m][j], 0, 0, 0);
    __syncthreads();   // drains prefetch; cur reads done before overwrite
  }

  // epilogue: out = acc + ub*D (C/D: col=lane&15, row=(lane>>4)*4+q)
  const int cr = (lane >> 4) * 4;
  const int cc = lane & 15;
#pragma unroll
  for (int m = 0; m < 2; m++)
#pragma unroll
    for (int j = 0; j < 4; j++) {
      const int rowg = bm + wr * 32 + m * 16 + cr;
      const int col = bn + wc * 64 + j * 16 + cc;
      const float d = Dv[col];
#pragma unroll
      for (int q = 0; q < 4; q++) {
        const size_t idx = (size_t)(rowg + q) * H_DIM + col;
        out[idx] = fmaf(bf2f(ub[idx]), d, acc[m][j][q]);
      }
    }
}

extern "C" void kernel_launch(void* const* d_in, const int* in_sizes, int n_in,
                              void* d_out, int out_size, void* d_ws, size_t ws_size,
                              hipStream_t stream) {
  const float* u      = (const float*)d_in[0];  // (L, H)
  const float* A_diag = (const float*)d_in[1];
  const float* G_diag = (const float*)d_in[2];
  const float* dt     = (const float*)d_in[3];
  const float* B      = (const float*)d_in[4];  // (P, H, 2)
  const float* C      = (const float*)d_in[5];  // (H, P, 2)
  const float* D      = (const float*)d_in[6];  // (H,)
  float* out = (float*)d_out;

  // Workspace: ys16 33.55MB | ub 8.39 | W1b 0.5 | W2b 0.5 | prm | finals 4 | carry 4 | aT/bT 128KB
  char* w = (char*)d_ws;
  unsigned short* ys16 = (unsigned short*)w;                               // L*1024 bf16 (as uints)
  unsigned short* ub   = (unsigned short*)(w + (size_t)L_SEQ * 1024 * 2);  // L*256 bf16
  unsigned short* W1b  = ub + (size_t)L_SEQ * H_DIM;                       // k-packed
  unsigned short* W2b  = W1b + 1024 * H_DIM;                               // k-packed
  float* prm    = (float*)(W2b + H_DIM * 1024);                            // 10*512 (pad 8192)
  float* finals = prm + 8192;                                              // NC*P*4
  float* carryb = finals + (size_t)NC * P_DIM * 4;                         // NC*P*4
  float* aT     = carryb + (size_t)NC * P_DIM * 4;                         // 32*512
  float* bT     = aT + 32 * P_DIM;                                         // 32*512

  prep_all<<<2 + 1024 + 1024 + 4096, 256, 0, stream>>>(
      A_diag, G_diag, dt, B, C, u, prm, W1b, W2b, ub, aT, bT);

  // GEMM1 + fused local scan -> ys_local + finals (no Bu materialization)
  gemm1_scan<<<dim3(L_SEQ / 128, 1024 / 128), 256, 0, stream>>>(
      ub, W1b, (unsigned int*)ys16, prm, (float4*)finals);

  scan_carry<<<P_DIM, NC, 0, stream>>>(
      (const float4*)finals, prm, (float4*)carryb);

  // elementwise carry correction, in place (ys_local -> ys)
  correct_ys<<<(L_SEQ * P_DIM / 4) / 256, 256, 0, stream>>>(
      (unsigned int*)ys16, (const float4*)carryb, aT, bT);

  // GEMM2 lean: grid (256, 2), 24KB LDS, double-buffered pipeline
  gemm2_lean<<<dim3(L_SEQ / 64, H_DIM / 128), 256, 0, stream>>>(
      ys16, W2b, ub, D, out);
}

// Round 17
// 78.635 us; speedup vs baseline: 1.4455x; 1.1221x over previous
//
#include <hip/hip_runtime.h>
#include <math.h>

// Problem constants: L=16384, H=256, P=512.
#define L_SEQ 16384
#define H_DIM 256
#define P_DIM 512
#define CL 32                 // scan chunk length
#define NC (L_SEQ / CL)       // 512 chunks

typedef __attribute__((ext_vector_type(8))) short bf16x8;   // MFMA A/B fragment (4 VGPR)
typedef __attribute__((ext_vector_type(4))) float f32x4;    // MFMA C/D fragment

static __device__ __forceinline__ unsigned short f2bf(float f) {
  unsigned int u = __builtin_bit_cast(unsigned int, f);
  u += 0x7FFFu + ((u >> 16) & 1u);
  return (unsigned short)(u >> 16);
}
static __device__ __forceinline__ float bflo(unsigned int v) {
  return __builtin_bit_cast(float, v << 16);
}
static __device__ __forceinline__ float bfhi(unsigned int v) {
  return __builtin_bit_cast(float, v & 0xFFFF0000u);
}
static __device__ __forceinline__ float bf2f(unsigned short s) {
  return __builtin_bit_cast(float, (unsigned int)s << 16);
}
static __device__ __forceinline__ unsigned int pack2(float r, float i) {
  return (unsigned int)f2bf(r) | ((unsigned int)f2bf(i) << 16);
}

// Weights K-PACKED: unit = (k>>3)*N + n, element = unit*8 + (k&7).
// prep branches: [0,2): params + a/b tables (row2 of M^{t+1}, t=0..31);
// [2,1026): W1b; [1026,2050): W2b; [2050,6146): cast u->ub.
__global__ __launch_bounds__(256) void prep_all(
    const float* __restrict__ A_diag, const float* __restrict__ G_diag,
    const float* __restrict__ dt, const float* __restrict__ B,
    const float* __restrict__ C, const float* __restrict__ u,
    float* __restrict__ prm, unsigned short* __restrict__ W1b,
    unsigned short* __restrict__ W2b, unsigned short* __restrict__ ub,
    float* __restrict__ aT, float* __restrict__ bT) {
  const int b = blockIdx.x;
  const int t = threadIdx.x;
  if (b < 2) {
    int p = b * 256 + t;
    float dts = 1.0f / (1.0f + expf(-dt[p]));
    float G = fmaxf(G_diag[p], 0.0f);
    float g = dts * G;
    float root = sqrtf(1.0f - g);
    float denom = fmaxf(dts * dts, 1e-6f);
    float A_low  = (2.0f - g - 2.0f * root) / denom;
    float A_high = (2.0f - g + 2.0f * root) / denom;
    float Ad = A_diag[p];
    float A = A_low + fmaxf(Ad - A_low, 0.0f) - fmaxf(Ad - A_high, 0.0f);
    float m00 = 1.0f - g;
    float m01 = -dts * A;
    float m10 = dts * (1.0f - g);
    float m11 = 1.0f - dts * dts * A;
    // a/b tables: cur = M^{t+1}, store its second row; cur = M*cur
    float e00 = m00, e01 = m01, e10 = m10, e11 = m11;
    for (int s = 0; s < 32; s++) {
      aT[s * P_DIM + p] = e10;
      bT[s * P_DIM + p] = e11;
      float f00 = m00 * e00 + m01 * e10;
      float f01 = m00 * e01 + m01 * e11;
      float f10 = m10 * e00 + m11 * e10;
      float f11 = m10 * e01 + m11 * e11;
      e00 = f00; e01 = f01; e10 = f10; e11 = f11;
    }
    // Mc = M^32 (5 squarings)
    float c00 = m00, c01 = m01, c10 = m10, c11 = m11;
#pragma unroll
    for (int i = 0; i < 5; i++) {
      float n00 = c00 * c00 + c01 * c10;
      float n01 = c00 * c01 + c01 * c11;
      float n10 = c10 * c00 + c11 * c10;
      float n11 = c10 * c01 + c11 * c11;
      c00 = n00; c01 = n01; c10 = n10; c11 = n11;
    }
    prm[0 * P_DIM + p] = m00;
    prm[1 * P_DIM + p] = m01;
    prm[2 * P_DIM + p] = m10;
    prm[3 * P_DIM + p] = m11;
    prm[4 * P_DIM + p] = dts;
    prm[5 * P_DIM + p] = dts * dts;
    prm[6 * P_DIM + p] = c00;
    prm[7 * P_DIM + p] = c01;
    prm[8 * P_DIM + p] = c10;
    prm[9 * P_DIM + p] = c11;
  } else if (b < 2 + 1024) {
    int idx = (b - 2) * 256 + t;          // n=2p+c in [0,1024), k=h in [0,256)
    int n = idx >> 8;
    int k = idx & 255;
    int p = n >> 1, c = n & 1;
    W1b[((size_t)(k >> 3) * 1024 + n) * 8 + (k & 7)] = f2bf(B[(p * H_DIM + k) * 2 + c]);
  } else if (b < 2 + 2048) {
    int idx = (b - 1026) * 256 + t;       // n=h in [0,256), k=2p+c in [0,1024)
    int h = idx >> 10;
    int k = idx & 1023;
    int p = k >> 1, c = k & 1;
    float v = C[(h * P_DIM + p) * 2 + c];
    W2b[((size_t)(k >> 3) * 256 + h) * 8 + (k & 7)] = f2bf(c ? -v : v);
  } else {
    int idx = (b - 2050) * 256 + t;       // cast u
    float4 v = ((const float4*)u)[idx];
    ushort4 o;
    o.x = f2bf(v.x); o.y = f2bf(v.y); o.z = f2bf(v.z); o.w = f2bf(v.w);
    ((ushort4*)ub)[idx] = o;
  }
}

// GEMM1 + fused local scan. 128x128 tile, 4 waves, BK=32, k-packed LDS.
// NO Bu global write: C-tile goes to LDS stg only; the fused scan then writes
// ys_local (pre-carry x2 per t, packed bf16) + chunk finals.
__global__ __launch_bounds__(256) void gemm1_scan(
    const unsigned short* __restrict__ A, const unsigned short* __restrict__ W,
    unsigned int* __restrict__ ys,              // ys_local, [L][512] packed
    const float* __restrict__ prm, float4* __restrict__ finals) {
  constexpr int K = H_DIM;
  __shared__ unsigned short tA[128 * 32];    // 8KB k-packed [kg][r][8]
  __shared__ unsigned short tW[128 * 32];    // 8KB k-packed [kg][n][8]
  __shared__ unsigned short stg[128 * 132];  // 33KB C-tile stage, padded stride
  const int tid = threadIdx.x;
  const int lane = tid & 63;
  const int wid = tid >> 6;
  const int wr = wid >> 1;
  const int wc = wid & 1;
  const int bm = blockIdx.x * 128;
  const int bn = blockIdx.y * 128;

  f32x4 acc[4][4] = {};
  const int rA = lane & 15;
  const int g = lane >> 4;

  for (int k0 = 0; k0 < K; k0 += 32) {
    __syncthreads();
#pragma unroll
    for (int c = wid; c < 8; c += 4) {        // A-tile: 512 units (kg*128 + r)
      const int unit = c * 64 + lane;
      const int kg = unit >> 7, r = unit & 127;
      const unsigned short* src = A + ((size_t)(bm + r) * 32 + (k0 >> 3) + kg) * 8;
      __builtin_amdgcn_global_load_lds(
          (const __attribute__((address_space(1))) void*)src,
          (__attribute__((address_space(3))) void*)(tA + c * 512), 16, 0, 0);
    }
#pragma unroll
    for (int c = wid; c < 8; c += 4) {        // W-tile: 512 units (kg*128 + n)
      const int unit = c * 64 + lane;
      const int kg = unit >> 7, n = unit & 127;
      const unsigned short* src = W + ((size_t)((k0 >> 3) + kg) * 1024 + bn + n) * 8;
      __builtin_amdgcn_global_load_lds(
          (const __attribute__((address_space(1))) void*)src,
          (__attribute__((address_space(3))) void*)(tW + c * 512), 16, 0, 0);
    }
    __syncthreads();

    bf16x8 af[4], wf[4];
#pragma unroll
    for (int i = 0; i < 4; i++)
      af[i] = *(const bf16x8*)&tA[(g * 128 + wr * 64 + i * 16 + rA) * 8];
#pragma unroll
    for (int j = 0; j < 4; j++)
      wf[j] = *(const bf16x8*)&tW[(g * 128 + wc * 64 + j * 16 + rA) * 8];
#pragma unroll
    for (int i = 0; i < 4; i++)
#pragma unroll
      for (int j = 0; j < 4; j++)
        acc[i][j] = __builtin_amdgcn_mfma_f32_16x16x32_bf16(af[i], wf[j], acc[i][j], 0, 0, 0);
  }

  // C-tile -> LDS stage only (C/D: col=lane&15, row=(lane>>4)*4+q)
  const int cr = (lane >> 4) * 4;
  const int cc = lane & 15;
#pragma unroll
  for (int i = 0; i < 4; i++)
#pragma unroll
    for (int j = 0; j < 4; j++) {
      const int rl = wr * 64 + i * 16 + cr;
      const int clc = wc * 64 + j * 16 + cc;
#pragma unroll
      for (int q = 0; q < 4; q++)
        stg[(rl + q) * 132 + clc] = f2bf(acc[i][j][q]);
    }

  // ---- fused local scan: 4 chunks x 64 p; writes ys_local + finals
  __syncthreads();
  {
    const int i = tid >> 6;            // chunk within tile (0..3)
    const int pl = tid & 63;
    const int p = (bn >> 1) + pl;
    const int cglob = blockIdx.x * 4 + i;
    float m00 = prm[0 * P_DIM + p], m01 = prm[1 * P_DIM + p];
    float m10 = prm[2 * P_DIM + p], m11 = prm[3 * P_DIM + p];
    float dts = prm[4 * P_DIM + p], dts2 = prm[5 * P_DIM + p];
    float x1r = 0.f, x2r = 0.f, x1i = 0.f, x2i = 0.f;
    const unsigned int* stg32 = (const unsigned int*)stg;   // dword idx = row*66 + pl
    unsigned int* dst = ys + (size_t)(bm + i * 32) * P_DIM + p;
#pragma unroll 8
    for (int s = 0; s < CL; s++) {
      unsigned int v = stg32[(i * 32 + s) * 66 + pl];
      float bx = bflo(v), by = bfhi(v);
      float n1r = fmaf(m00, x1r, fmaf(m01, x2r, dts * bx));
      float n2r = fmaf(m10, x1r, fmaf(m11, x2r, dts2 * bx));
      float n1i = fmaf(m00, x1i, fmaf(m01, x2i, dts * by));
      float n2i = fmaf(m10, x1i, fmaf(m11, x2i, dts2 * by));
      dst[(size_t)s * P_DIM] = pack2(n2r, n2i);   // ys_local = x2 (pre-carry)
      x1r = n1r; x2r = n2r; x1i = n1i; x2i = n2i;
    }
    finals[(size_t)cglob * P_DIM + p] = make_float4(x1r, x2r, x1i, x2i);
  }
}

// Phase B: Hillis-Steele over NC=512 chunks, one block per p, 512 threads.
__global__ __launch_bounds__(NC) void scan_carry(
    const float4* __restrict__ finals, const float* __restrict__ prm,
    float4* __restrict__ carry) {
  int p = blockIdx.x;
  int c = threadIdx.x;
  __shared__ float4 sb[NC];
  float m00 = prm[6 * P_DIM + p], m01 = prm[7 * P_DIM + p];
  float m10 = prm[8 * P_DIM + p], m11 = prm[9 * P_DIM + p];
  float4 b = finals[c * P_DIM + p];
  for (int o = 1; o < NC; o <<= 1) {
    sb[c] = b;
    __syncthreads();
    float4 nb = (c >= o) ? sb[c - o] : make_float4(0.f, 0.f, 0.f, 0.f);
    __syncthreads();
    b.x = fmaf(m00, nb.x, fmaf(m01, nb.y, b.x));
    b.y = fmaf(m10, nb.x, fmaf(m11, nb.y, b.y));
    b.z = fmaf(m00, nb.z, fmaf(m01, nb.w, b.z));
    b.w = fmaf(m10, nb.z, fmaf(m11, nb.w, b.w));
    float n00 = m00 * m00 + m01 * m10;
    float n01 = m00 * m01 + m01 * m11;
    float n10 = m10 * m00 + m11 * m10;
    float n11 = m10 * m01 + m11 * m11;
    m00 = n00; m01 = n01; m10 = n10; m11 = n11;
  }
  if (c + 1 < NC) carry[(c + 1) * P_DIM + p] = b;
  if (c == 0) carry[p] = make_float4(0.f, 0.f, 0.f, 0.f);
}

// Elementwise carry correction, in-place: ys[t][p] += a[t&31][p]*x1in + b*x2in
// (re and im share real coefficients). Fully parallel, coalesced uint4.
__global__ __launch_bounds__(256) void correct_ys(
    unsigned int* __restrict__ ys, const float4* __restrict__ carry,
    const float* __restrict__ aT, const float* __restrict__ bT) {
  const int i4 = blockIdx.x * 256 + threadIdx.x;   // uint4 index
  const int tg = i4 >> 7;                          // global row t
  const int p0 = (i4 & 127) * 4;
  const int c = tg >> 5, t = tg & 31;
  uint4 v = ((const uint4*)ys)[i4];
  const float4 a = *(const float4*)&aT[t * P_DIM + p0];
  const float4 b = *(const float4*)&bT[t * P_DIM + p0];
  const float4* cb = carry + (size_t)c * P_DIM + p0;
  float4 x0 = cb[0], x1 = cb[1], x2 = cb[2], x3 = cb[3];
  v.x = pack2(bflo(v.x) + a.x * x0.x + b.x * x0.y, bfhi(v.x) + a.x * x0.z + b.x * x0.w);
  v.y = pack2(bflo(v.y) + a.y * x1.x + b.y * x1.y, bfhi(v.y) + a.y * x1.z + b.y * x1.w);
  v.z = pack2(bflo(v.z) + a.z * x2.x + b.z * x2.y, bfhi(v.z) + a.z * x2.z + b.z * x2.w);
  v.w = pack2(bflo(v.w) + a.w * x3.x + b.w * x3.y, bfhi(v.w) + a.w * x3.z + b.w * x3.w);
  ((uint4*)ys)[i4] = v;
}

// GEMM2 m97-clone: out[L][256] = ys[L][1024] @ W2b^T + ub*D.
// 64x64 tile, BK=64, grid (256,4) = 1024 blocks -> 4 blocks/CU, 16 waves/CU
// (the occupancy every previous gemm2 variant lacked). 16KB LDS, 2-barrier
// loop, 8 MFMA + 4 gload + 8 ds_read per iter.
// A LDS [row][8 segs of 16B], seg ^= row&7 via PRE-SWIZZLED global source
// (rule #21: linear dest + same XOR on read) -> 2 lanes/bank (free).
// W LDS k-packed [kg][n][8] -> conflict-free (proven in gemm1).
__global__ __launch_bounds__(256) void gemm2_m97(
    const unsigned short* __restrict__ ys16, const unsigned short* __restrict__ W2b,
    const unsigned short* __restrict__ ub, const float* __restrict__ Dv,
    float* __restrict__ out) {
  __shared__ unsigned short tA[64 * 64];     // 8KB
  __shared__ unsigned short tW[8 * 64 * 8];  // 8KB
  const int tid = threadIdx.x;
  const int lane = tid & 63;
  const int wid = tid >> 6;
  const int wr = wid >> 1;          // wave row half (32 rows)
  const int wc = wid & 1;           // wave col half (32 cols)
  const int bm = blockIdx.x * 64;
  const int bn = blockIdx.y * 64;
  const int rA = lane & 15;
  const int g = lane >> 4;

  f32x4 acc[2][2] = {};

  for (int k0 = 0; k0 < 1024; k0 += 64) {
    __syncthreads();
#pragma unroll
    for (int c = 0; c < 2; c++) {   // A: 512 units (row*8 + seg), 2 gloads/wave
      const int u = wid * 128 + c * 64 + lane;
      const int row = u >> 3;
      const int sseg = (u & 7) ^ (row & 7);          // pre-swizzled source seg
      const unsigned short* src = ys16 + (size_t)(bm + row) * 1024 + k0 + sseg * 8;
      __builtin_amdgcn_global_load_lds(
          (const __attribute__((address_space(1))) void*)src,
          (__attribute__((address_space(3))) void*)(tA + (wid * 128 + c * 64) * 8), 16, 0, 0);
    }
#pragma unroll
    for (int c = 0; c < 2; c++) {   // W: 512 units (kg*64 + n), 2 gloads/wave
      const int u = wid * 128 + c * 64 + lane;
      const int kg = u >> 6, n = u & 63;
      const unsigned short* src = W2b + (((size_t)(k0 >> 3) + kg) * 256 + bn + n) * 8;
      __builtin_amdgcn_global_load_lds(
          (const __attribute__((address_space(1))) void*)src,
          (__attribute__((address_space(3))) void*)(tW + (wid * 128 + c * 64) * 8), 16, 0, 0);
    }
    __syncthreads();

    bf16x8 af[2][2], wf[2][2];
#pragma unroll
    for (int kk = 0; kk < 2; kk++) {
#pragma unroll
      for (int m = 0; m < 2; m++) {
        const int row = wr * 32 + m * 16 + rA;
        const int seg = (kk * 4 + g) ^ (row & 7);    // same XOR on read
        af[kk][m] = *(const bf16x8*)&tA[(row * 8 + seg) * 8];
      }
#pragma unroll
      for (int j = 0; j < 2; j++) {
        const int n = wc * 32 + j * 16 + rA;
        wf[kk][j] = *(const bf16x8*)&tW[((kk * 4 + g) * 64 + n) * 8];
      }
    }
#pragma unroll
    for (int kk = 0; kk < 2; kk++)
#pragma unroll
      for (int m = 0; m < 2; m++)
#pragma unroll
        for (int j = 0; j < 2; j++)
          acc[m][j] = __builtin_amdgcn_mfma_f32_16x16x32_bf16(af[kk][m], wf[kk][j], acc[m][j], 0, 0, 0);
  }

  // epilogue: out = acc + ub*D (C/D: col=lane&15, row=(lane>>4)*4+q)
  const int cr = (lane >> 4) * 4;
  const int cc = lane & 15;
#pragma unroll
  for (int m = 0; m < 2; m++)
#pragma unroll
    for (int j = 0; j < 2; j++) {
      const int rowg = bm + wr * 32 + m * 16 + cr;
      const int col = bn + wc * 32 + j * 16 + cc;
      const float d = Dv[col];
#pragma unroll
      for (int q = 0; q < 4; q++) {
        const size_t idx = (size_t)(rowg + q) * H_DIM + col;
        out[idx] = fmaf(bf2f(ub[idx]), d, acc[m][j][q]);
      }
    }
}

extern "C" void kernel_launch(void* const* d_in, const int* in_sizes, int n_in,
                              void* d_out, int out_size, void* d_ws, size_t ws_size,
                              hipStream_t stream) {
  const float* u      = (const float*)d_in[0];  // (L, H)
  const float* A_diag = (const float*)d_in[1];
  const float* G_diag = (const float*)d_in[2];
  const float* dt     = (const float*)d_in[3];
  const float* B      = (const float*)d_in[4];  // (P, H, 2)
  const float* C      = (const float*)d_in[5];  // (H, P, 2)
  const float* D      = (const float*)d_in[6];  // (H,)
  float* out = (float*)d_out;

  // Workspace: ys16 33.55MB | ub 8.39 | W1b 0.5 | W2b 0.5 | prm | finals 4 | carry 4 | aT/bT 128KB
  char* w = (char*)d_ws;
  unsigned short* ys16 = (unsigned short*)w;                               // L*1024 bf16 (as uints)
  unsigned short* ub   = (unsigned short*)(w + (size_t)L_SEQ * 1024 * 2);  // L*256 bf16
  unsigned short* W1b  = ub + (size_t)L_SEQ * H_DIM;                       // k-packed
  unsigned short* W2b  = W1b + 1024 * H_DIM;                               // k-packed
  float* prm    = (float*)(W2b + H_DIM * 1024);                            // 10*512 (pad 8192)
  float* finals = prm + 8192;                                              // NC*P*4
  float* carryb = finals + (size_t)NC * P_DIM * 4;                         // NC*P*4
  float* aT     = carryb + (size_t)NC * P_DIM * 4;                         // 32*512
  float* bT     = aT + 32 * P_DIM;                                         // 32*512

  prep_all<<<2 + 1024 + 1024 + 4096, 256, 0, stream>>>(
      A_diag, G_diag, dt, B, C, u, prm, W1b, W2b, ub, aT, bT);

  // GEMM1 + fused local scan -> ys_local + finals (no Bu materialization)
  gemm1_scan<<<dim3(L_SEQ / 128, 1024 / 128), 256, 0, stream>>>(
      ub, W1b, (unsigned int*)ys16, prm, (float4*)finals);

  scan_carry<<<P_DIM, NC, 0, stream>>>(
      (const float4*)finals, prm, (float4*)carryb);

  // elementwise carry correction, in place (ys_local -> ys)
  correct_ys<<<(L_SEQ * P_DIM / 4) / 256, 256, 0, stream>>>(
      (unsigned int*)ys16, (const float4*)carryb, aT, bT);

  // GEMM2 m97-clone: grid (256,4) = 1024 blocks, 4/CU, 16 waves/CU
  gemm2_m97<<<dim3(L_SEQ / 64, H_DIM / 64), 256, 0, stream>>>(
      ys16, W2b, ub, D, out);
}